// Round 1
// 11606.249 us; speedup vs baseline: 1.2945x; 1.2945x over previous
//
#include <hip/hip_runtime.h>
#include <math.h>

#define N_NODES 1024
#define HID 64
#define BATCH 16
#define TSTEPS 288
#define PWIN 24
#define PL 12
#define EMB 16
#define HOR 12
#define NBH (N_NODES*BATCH*HID)   // 1048576 elems per time-slice

typedef __attribute__((ext_vector_type(4))) short short4_t;

__global__ __launch_bounds__(256) void zero_k(float* p, int n) {
    int i = blockIdx.x*256 + threadIdx.x;
    if (i < n) p[i] = 0.f;
}

// block per (p,n): x[p][n][b][h] = sum_t src[b, p*12+t, n]*vw[t,h] + pe[p,h]
// quantized to i16 with per-(p,n) amax scale
__global__ __launch_bounds__(256) void embedq_k(
    const float* __restrict__ src, const float* __restrict__ vw,
    short* __restrict__ xq, float* __restrict__ xsc)
{
    int blk = blockIdx.x;            // p*1024 + n
    int p = blk >> 10, n = blk & 1023;
    int t = threadIdx.x;
    __shared__ float sv[192];        // src[b][tt]
    __shared__ float wv[PL*HID];     // 768
    __shared__ float red[256];
    if (t < 192) {
        int b = t / 12, tt = t % 12;
        sv[t] = src[((size_t)b*TSTEPS + p*PL + tt)*N_NODES + n];
    }
    for (int i = t; i < PL*HID; i += 256) wv[i] = vw[i];
    __syncthreads();
    float vals[4]; float amax = 0.f;
#pragma unroll
    for (int q = 0; q < 4; ++q) {
        int i = q*256 + t;           // b*64 + h
        int b = i >> 6, h = i & 63;
        float acc = 0.f;
#pragma unroll
        for (int tt = 0; tt < PL; ++tt) acc += sv[b*12 + tt] * wv[tt*HID + h];
        float d = expf(-(float)(h & ~1) * (float)(9.210340371976184/64.0));
        float arg = (float)p * d;
        acc += (h & 1) ? cosf(arg) : sinf(arg);
        vals[q] = acc; amax = fmaxf(amax, fabsf(acc));
    }
    red[t] = amax; __syncthreads();
    for (int s2 = 128; s2 > 0; s2 >>= 1) {
        if (t < s2) red[t] = fmaxf(red[t], red[t + s2]);
        __syncthreads();
    }
    amax = red[0];
    float inv = (amax > 0.f) ? 32767.f/amax : 0.f;
    short* xp = xq + (size_t)blk*1024;
#pragma unroll
    for (int q = 0; q < 4; ++q)
        xp[q*256 + t] = (short)__float2int_rn(vals[q]*inv);
    if (t == 0) xsc[blk] = (amax > 0.f) ? amax/32767.f : 0.f;
}

// A[n][m] = softmax_m(relu(emb[n]·emb[m]))
__global__ __launch_bounds__(256) void adj_k(const float* __restrict__ emb, float* __restrict__ A)
{
    __shared__ float en[EMB];
    __shared__ float red[256];
    int n = blockIdx.x, t = threadIdx.x;
    if (t < EMB) en[t] = emb[n*EMB + t];
    __syncthreads();
    float v[4]; float mx = 0.f;
#pragma unroll
    for (int q = 0; q < 4; ++q) {
        int m = q*256 + t;
        float dot = 0.f;
#pragma unroll
        for (int e = 0; e < EMB; ++e) dot += en[e]*emb[m*EMB + e];
        v[q] = fmaxf(dot, 0.f);
        mx = fmaxf(mx, v[q]);
    }
    red[t] = mx; __syncthreads();
    for (int s2 = 128; s2 > 0; s2 >>= 1) {
        if (t < s2) red[t] = fmaxf(red[t], red[t + s2]);
        __syncthreads();
    }
    mx = red[0]; __syncthreads();
    float sum = 0.f;
#pragma unroll
    for (int q = 0; q < 4; ++q) { v[q] = expf(v[q] - mx); sum += v[q]; }
    red[t] = sum; __syncthreads();
    for (int s2 = 128; s2 > 0; s2 >>= 1) {
        if (t < s2) red[t] += red[t + s2];
        __syncthreads();
    }
    float inv = 1.f / red[0];
#pragma unroll
    for (int q = 0; q < 4; ++q) A[(size_t)n*N_NODES + q*256 + t] = v[q]*inv;
}

// gwT[e][o][kc] <- gwl[e][kc][o]  (tiny one-time transpose per layer weight)
template<int OUT>
__global__ __launch_bounds__(256) void wtrans_k(
    const float* __restrict__ gwl, float* __restrict__ gwT)
{
    int idx = blockIdx.x*256 + threadIdx.x;   // e*OUT*256 total, exact grid
    int kc = idx & 255;
    int rest = idx >> 8;
    int o = rest % OUT;
    int e = rest / OUT;
    gwT[idx] = gwl[((size_t)e*256 + kc)*OUT + o];
}

// W[n][o][kc] = sum_e emb[n][e]*gwT[e][o][kc], i16-quantized with per-(n,o) row scale.
// Block handles 4 nodes; wave w handles rows o = w, w+4, ...; lane covers kc = lane*4..+3.
// Coalesced float4 reads (shared across the 4 nodes), wave-local shuffle amax, single pass.
template<int OUT>
__global__ __launch_bounds__(256) void wnodeq2_k(
    const float* __restrict__ emb, const float* __restrict__ gwT,
    short* __restrict__ WQ, float* __restrict__ wsc)
{
    int t = threadIdx.x;
    int n0 = blockIdx.x * 4;
    int lane = t & 63, w = t >> 6;
    __shared__ float se[4][EMB];
    if (t < 4*EMB) se[t >> 4][t & 15] = emb[(n0 + (t >> 4))*EMB + (t & 15)];
    __syncthreads();
    for (int o = w; o < OUT; o += 4) {
        const float* gp = gwT + (size_t)o*256 + lane*4;
        float4 s[4];
#pragma unroll
        for (int ng = 0; ng < 4; ++ng) s[ng] = make_float4(0.f, 0.f, 0.f, 0.f);
#pragma unroll
        for (int e = 0; e < EMB; ++e) {
            float4 g = *(const float4*)(gp + (size_t)e*(OUT*256));
#pragma unroll
            for (int ng = 0; ng < 4; ++ng) {
                float c = se[ng][e];
                s[ng].x += c*g.x; s[ng].y += c*g.y; s[ng].z += c*g.z; s[ng].w += c*g.w;
            }
        }
#pragma unroll
        for (int ng = 0; ng < 4; ++ng) {
            float amax = fmaxf(fmaxf(fabsf(s[ng].x), fabsf(s[ng].y)),
                               fmaxf(fabsf(s[ng].z), fabsf(s[ng].w)));
#pragma unroll
            for (int d = 32; d > 0; d >>= 1) amax = fmaxf(amax, __shfl_xor(amax, d));
            float inv = (amax > 0.f) ? 32767.f/amax : 0.f;
            short4_t q;
            q.x = (short)__float2int_rn(s[ng].x*inv);
            q.y = (short)__float2int_rn(s[ng].y*inv);
            q.z = (short)__float2int_rn(s[ng].z*inv);
            q.w = (short)__float2int_rn(s[ng].w*inv);
            *(short4_t*)(WQ + ((size_t)(n0+ng)*OUT + o)*256 + lane*4) = q;
            if (lane == 0) wsc[(n0+ng)*OUT + o] = (amax > 0.f) ? amax/32767.f : 0.f;
        }
    }
}

__global__ __launch_bounds__(256) void bias_k(const float* __restrict__ emb,
                        const float* __restrict__ gbl, float* __restrict__ bn, int OUT)
{
    int idx = blockIdx.x*256 + threadIdx.x;
    if (idx >= N_NODES*OUT) return;
    int n = idx / OUT, o = idx % OUT;
    float s = 0.f;
#pragma unroll
    for (int e = 0; e < EMB; ++e) s += emb[n*EMB + e]*gbl[e*OUT + o];
    bn[idx] = s;
}

// out[r][j] = sum_m A[r][m]*B(m,j), 1024^3, f32 accumulate/output.
// MODE 0: B = f32 S1[m*1024+j]
// MODE 1: B = z(m,j)*h(m,j); z from zr [m][b][128], h from S2 [m][1024]
// MODE 2: B = i16 S1[m*1024+j] * bscale[m]
template<int MODE>
__global__ __launch_bounds__(256) void gemm_k(
    const float* __restrict__ Amat, const void* __restrict__ S1v,
    const float* __restrict__ S2, const float* __restrict__ bscale,
    float* __restrict__ out)
{
    __shared__ float As[16][68];
    __shared__ float Bs[16][68];
    int tid = threadIdx.x;
    int tx = tid & 15, ty = tid >> 4;
    int rowBase = blockIdx.y*64, colBase = blockIdx.x*64;
    float acc[4][4];
#pragma unroll
    for (int i = 0; i < 4; ++i)
#pragma unroll
        for (int j = 0; j < 4; ++j) acc[i][j] = 0.f;
    int lr = tid >> 2, lkq = tid & 3;
    int lk = tid >> 4, lj = (tid & 15) * 4;
    for (int k0 = 0; k0 < 1024; k0 += 16) {
        float4 a4 = *(const float4*)(Amat + (size_t)(rowBase + lr)*1024 + k0 + lkq*4);
        As[lkq*4+0][lr] = a4.x; As[lkq*4+1][lr] = a4.y;
        As[lkq*4+2][lr] = a4.z; As[lkq*4+3][lr] = a4.w;
        int m = k0 + lk, j = colBase + lj;
        float4 b4;
        if (MODE == 0) {
            b4 = *(const float4*)((const float*)S1v + (size_t)m*1024 + j);
        } else if (MODE == 2) {
            short4_t q4 = *(const short4_t*)((const short*)S1v + (size_t)m*1024 + j);
            float s = bscale[m];
            b4 = make_float4((float)q4.x*s, (float)q4.y*s, (float)q4.z*s, (float)q4.w*s);
        } else {
            float4 z4 = *(const float4*)((const float*)S1v + ((size_t)m*16 + (j >> 6))*128 + (j & 63));
            float4 h4 = *(const float4*)(S2 + (size_t)m*1024 + j);
            b4 = make_float4(z4.x*h4.x, z4.y*h4.y, z4.z*h4.z, z4.w*h4.w);
        }
        *(float4*)(&Bs[lk][lj]) = b4;
        __syncthreads();
#pragma unroll
        for (int kk = 0; kk < 16; ++kk) {
            float4 av = *(const float4*)(&As[kk][ty*4]);
            float4 bv = *(const float4*)(&Bs[kk][tx*4]);
            acc[0][0] += av.x*bv.x; acc[0][1] += av.x*bv.y; acc[0][2] += av.x*bv.z; acc[0][3] += av.x*bv.w;
            acc[1][0] += av.y*bv.x; acc[1][1] += av.y*bv.y; acc[1][2] += av.y*bv.z; acc[1][3] += av.y*bv.w;
            acc[2][0] += av.z*bv.x; acc[2][1] += av.z*bv.y; acc[2][2] += av.z*bv.z; acc[2][3] += av.z*bv.w;
            acc[3][0] += av.w*bv.x; acc[3][1] += av.w*bv.y; acc[3][2] += av.w*bv.z; acc[3][3] += av.w*bv.w;
        }
        __syncthreads();
    }
#pragma unroll
    for (int i = 0; i < 4; ++i)
        *(float4*)(out + (size_t)(rowBase + ty*4 + i)*1024 + colBase + tx*4) =
            make_float4(acc[i][0], acc[i][1], acc[i][2], acc[i][3]);
}

// zr[n][b][o] = sigmoid( [x,h,Ax,Ah](n,b,:) · Wq[n](o,:)·ws[n][o] + bg[n][o] )
__global__ __launch_bounds__(256) void gate_k(
    const short* __restrict__ xq, const float* __restrict__ xsc,
    const float* __restrict__ hst, const float* __restrict__ axt,
    const float* __restrict__ aggh, const short* __restrict__ WQ,
    const float* __restrict__ wsc, const float* __restrict__ bg,
    float* __restrict__ zr)
{
    __shared__ float inp[16*256];
    int n = blockIdx.x, t = threadIdx.x;
    size_t nb = (size_t)n*1024;
    float sx = xsc[n];
    for (int i = t; i < 1024; i += 256) {
        int b = i >> 6, c = i & 63;
        inp[b*256 + c]       = (float)xq[nb + i] * sx;
        inp[b*256 + 64 + c]  = hst[nb + i];
        inp[b*256 + 128 + c] = axt[nb + i];
        inp[b*256 + 192 + c] = aggh[nb + i];
    }
    __syncthreads();
    int o = t & 127, g = t >> 7;
    const short* w = WQ + ((size_t)n*128 + o)*256;
    float ws = wsc[n*128 + o];
    float bias = bg[n*128 + o];
    float acc[8];
#pragma unroll
    for (int u = 0; u < 8; ++u) acc[u] = 0.f;
    for (int k0 = 0; k0 < 256; k0 += 4) {
        short4_t w4 = *(const short4_t*)(w + k0);
        float w0 = (float)w4.x, w1 = (float)w4.y, w2 = (float)w4.z, w3 = (float)w4.w;
#pragma unroll
        for (int u = 0; u < 8; ++u) {
            float4 iv = *(const float4*)(&inp[(g*8 + u)*256 + k0]);
            acc[u] += w0*iv.x + w1*iv.y + w2*iv.z + w3*iv.w;
        }
    }
#pragma unroll
    for (int u = 0; u < 8; ++u) {
        int b = g*8 + u;
        float pre = acc[u]*ws + bias;
        zr[((size_t)n*16 + b)*128 + o] = 1.f/(1.f + expf(-pre));
    }
}

// h_new = r*h + (1-r)*tanh([x, z*h, Ax, A(z*h)]·Wu[n]·ws[n][o] + bu); h f32 in-place,
// also writes h as i16 (scale 1/32767) into xq (next layer's input) + its scale.
__global__ __launch_bounds__(256) void upd_k(
    short* __restrict__ xq, float* __restrict__ xsc,
    float* __restrict__ hst, const float* __restrict__ axt,
    const float* __restrict__ aggzh, const float* __restrict__ zr,
    const short* __restrict__ WQ, const float* __restrict__ wsc,
    const float* __restrict__ bu)
{
    __shared__ float inp[16*256];
    int n = blockIdx.x, t = threadIdx.x;
    size_t nb = (size_t)n*1024;
    float sx = xsc[n];
    for (int i = t; i < 1024; i += 256) {
        int b = i >> 6, c = i & 63;
        float hv = hst[nb + i];
        float zv = zr[((size_t)n*16 + b)*128 + c];
        inp[b*256 + c]       = (float)xq[nb + i] * sx;
        inp[b*256 + 64 + c]  = zv * hv;
        inp[b*256 + 128 + c] = axt[nb + i];
        inp[b*256 + 192 + c] = aggzh[nb + i];
    }
    __syncthreads();
    int o = t & 63, g = t >> 6;
    const short* w = WQ + ((size_t)n*64 + o)*256;
    float ws = wsc[n*64 + o];
    float bias = bu[n*64 + o];
    float acc[4];
#pragma unroll
    for (int u = 0; u < 4; ++u) acc[u] = 0.f;
    for (int k0 = 0; k0 < 256; k0 += 4) {
        short4_t w4 = *(const short4_t*)(w + k0);
        float w0 = (float)w4.x, w1 = (float)w4.y, w2 = (float)w4.z, w3 = (float)w4.w;
#pragma unroll
        for (int u = 0; u < 4; ++u) {
            float4 iv = *(const float4*)(&inp[(g*4 + u)*256 + k0]);
            acc[u] += w0*iv.x + w1*iv.y + w2*iv.z + w3*iv.w;
        }
    }
#pragma unroll
    for (int u = 0; u < 4; ++u) {
        int b = g*4 + u;
        float r = zr[((size_t)n*16 + b)*128 + 64 + o];
        float hold = hst[nb + b*64 + o];
        float hc = tanhf(acc[u]*ws + bias);
        float hn = r*hold + (1.f - r)*hc;
        hst[nb + b*64 + o] = hn;
        xq[nb + b*64 + o] = (short)__float2int_rn(hn*32767.f);
    }
    if (t == 0) xsc[n] = 1.f/32767.f;
}

// out[b][o][n] = h[n][b][:]·ecw[o][:] + ecb[o]
__global__ __launch_bounds__(256) void endconv_k(
    const float* __restrict__ hst, const float* __restrict__ ecw,
    const float* __restrict__ ecb, float* __restrict__ out)
{
    int idx = blockIdx.x*256 + threadIdx.x;   // 196608
    int n = idx & 1023;
    int o = (idx >> 10) % HOR;
    int b = idx / (HOR*1024);
    float s = ecb[o];
#pragma unroll
    for (int hh = 0; hh < 64; ++hh)
        s += hst[((size_t)n*16 + b)*64 + hh] * ecw[o*64 + hh];
    out[idx] = s;
}

extern "C" void kernel_launch(void* const* d_in, const int* in_sizes, int n_in,
                              void* d_out, int out_size, void* d_ws, size_t ws_size,
                              hipStream_t stream)
{
    const float* source = (const float*)d_in[0];
    const float* emb    = (const float*)d_in[2];
    const float* vw     = (const float*)d_in[3];
    const float* gate_w = (const float*)d_in[4];
    const float* gate_b = (const float*)d_in[5];
    const float* upd_w  = (const float*)d_in[6];
    const float* upd_b  = (const float*)d_in[7];
    const float* ecw    = (const float*)d_in[8];
    const float* ecb    = (const float*)d_in[9];
    float* out = (float*)d_out;

    // ---- workspace carve: ~176 MB ----
    char* p = (char*)d_ws;
    float* A    = (float*)p;  p += (size_t)1048576*4;        //   4.0 MB
    short* WgQ  = (short*)p;  p += (size_t)33554432*2;       //  64.0 MB  [n][128][256] i16
    short* WuQ  = (short*)p;  p += (size_t)16777216*2;       //  32.0 MB  [n][64][256] i16
    float* swg  = (float*)p;  p += (size_t)131072*4;         //   0.5 MB  per (n,o)
    float* swu  = (float*)p;  p += (size_t)65536*4;          //   0.25 MB per (n,o)
    float* bgn  = (float*)p;  p += (size_t)131072*4;         //   0.5 MB
    float* bun  = (float*)p;  p += (size_t)65536*4;          //   0.25 MB
    short* xq   = (short*)p;  p += (size_t)25165824*2;       //  48.0 MB  [p][n][b][h] i16
    float* xsc  = (float*)p;  p += (size_t)24576*4;          //   0.1 MB  per (p,n)
    float* hbuf = (float*)p;  p += (size_t)1048576*4;        //   4.0 MB
    float* zrb  = (float*)p;  p += (size_t)2097152*4;        //   8.0 MB
    float* axh  = (float*)p;  p += (size_t)2097152*4;        //   8.0 MB (A@h | A@x)
    float* aggzh= (float*)p;  p += (size_t)1048576*4;        //   4.0 MB
    float* gwT  = (float*)p;                                  //   2.0 MB [e][o][kc] scratch
    float* axh0 = axh;                  // A@h
    float* axh1 = axh + 1048576;        // A@x_t

    embedq_k<<<24576, 256, 0, stream>>>(source, vw, xq, xsc);
    adj_k<<<1024, 256, 0, stream>>>(emb, A);

    for (int l = 0; l < 2; ++l) {
        wtrans_k<128><<<2048, 256, 0, stream>>>(gate_w + (size_t)l*524288, gwT);
        wnodeq2_k<128><<<256, 256, 0, stream>>>(emb, gwT, WgQ, swg);
        wtrans_k<64><<<1024, 256, 0, stream>>>(upd_w + (size_t)l*262144, gwT);
        wnodeq2_k<64><<<256, 256, 0, stream>>>(emb, gwT, WuQ, swu);
        bias_k<<<512, 256, 0, stream>>>(emb, gate_b + l*2048, bgn, 128);
        bias_k<<<256, 256, 0, stream>>>(emb, upd_b + l*1024, bun, 64);
        zero_k<<<4096, 256, 0, stream>>>(hbuf, 1048576);
        for (int ps = 0; ps < PWIN; ++ps) {
            short* xq_p  = xq  + (size_t)ps*NBH;
            float* xsc_p = xsc + (size_t)ps*1024;
            gemm_k<0><<<dim3(16,16), 256, 0, stream>>>(A, hbuf, nullptr, nullptr, axh0);
            gemm_k<2><<<dim3(16,16), 256, 0, stream>>>(A, xq_p, nullptr, xsc_p, axh1);
            gate_k<<<1024, 256, 0, stream>>>(xq_p, xsc_p, hbuf, axh1, axh0, WgQ, swg, bgn, zrb);
            gemm_k<1><<<dim3(16,16), 256, 0, stream>>>(A, zrb, hbuf, nullptr, aggzh);
            upd_k<<<1024, 256, 0, stream>>>(xq_p, xsc_p, hbuf, axh1, aggzh, zrb, WuQ, swu, bun);
        }
    }
    endconv_k<<<768, 256, 0, stream>>>(hbuf, ecw, ecb, out);
}

// Round 2
// 7917.830 us; speedup vs baseline: 1.8975x; 1.4658x over previous
//
#include <hip/hip_runtime.h>
#include <math.h>

#define N_NODES 1024
#define HID 64
#define BATCH 16
#define TSTEPS 288
#define PWIN 24
#define PL 12
#define EMB 16
#define HOR 12
#define NBH (N_NODES*BATCH*HID)   // 1048576 elems per time-slice

typedef __attribute__((ext_vector_type(4))) short short4_t;

// block per (p,n): x[p][n][b][h] = sum_t src[b, p*12+t, n]*vw[t,h] + pe[p,h]
// quantized to i16 with per-(p,n) amax scale
__global__ __launch_bounds__(256) void embedq_k(
    const float* __restrict__ src, const float* __restrict__ vw,
    short* __restrict__ xq, float* __restrict__ xsc)
{
    int blk = blockIdx.x;            // p*1024 + n
    int p = blk >> 10, n = blk & 1023;
    int t = threadIdx.x;
    __shared__ float sv[192];        // src[b][tt]
    __shared__ float wv[PL*HID];     // 768
    __shared__ float red[256];
    if (t < 192) {
        int b = t / 12, tt = t % 12;
        sv[t] = src[((size_t)b*TSTEPS + p*PL + tt)*N_NODES + n];
    }
    for (int i = t; i < PL*HID; i += 256) wv[i] = vw[i];
    __syncthreads();
    float vals[4]; float amax = 0.f;
#pragma unroll
    for (int q = 0; q < 4; ++q) {
        int i = q*256 + t;           // b*64 + h
        int b = i >> 6, h = i & 63;
        float acc = 0.f;
#pragma unroll
        for (int tt = 0; tt < PL; ++tt) acc += sv[b*12 + tt] * wv[tt*HID + h];
        float d = expf(-(float)(h & ~1) * (float)(9.210340371976184/64.0));
        float arg = (float)p * d;
        acc += (h & 1) ? cosf(arg) : sinf(arg);
        vals[q] = acc; amax = fmaxf(amax, fabsf(acc));
    }
    red[t] = amax; __syncthreads();
    for (int s2 = 128; s2 > 0; s2 >>= 1) {
        if (t < s2) red[t] = fmaxf(red[t], red[t + s2]);
        __syncthreads();
    }
    amax = red[0];
    float inv = (amax > 0.f) ? 32767.f/amax : 0.f;
    short* xp = xq + (size_t)blk*1024;
#pragma unroll
    for (int q = 0; q < 4; ++q)
        xp[q*256 + t] = (short)__float2int_rn(vals[q]*inv);
    if (t == 0) xsc[blk] = (amax > 0.f) ? amax/32767.f : 0.f;
}

// A[n][m] = softmax_m(relu(emb[n]·emb[m]))
__global__ __launch_bounds__(256) void adj_k(const float* __restrict__ emb, float* __restrict__ A)
{
    __shared__ float en[EMB];
    __shared__ float red[256];
    int n = blockIdx.x, t = threadIdx.x;
    if (t < EMB) en[t] = emb[n*EMB + t];
    __syncthreads();
    float v[4]; float mx = 0.f;
#pragma unroll
    for (int q = 0; q < 4; ++q) {
        int m = q*256 + t;
        float dot = 0.f;
#pragma unroll
        for (int e = 0; e < EMB; ++e) dot += en[e]*emb[m*EMB + e];
        v[q] = fmaxf(dot, 0.f);
        mx = fmaxf(mx, v[q]);
    }
    red[t] = mx; __syncthreads();
    for (int s2 = 128; s2 > 0; s2 >>= 1) {
        if (t < s2) red[t] = fmaxf(red[t], red[t + s2]);
        __syncthreads();
    }
    mx = red[0]; __syncthreads();
    float sum = 0.f;
#pragma unroll
    for (int q = 0; q < 4; ++q) { v[q] = expf(v[q] - mx); sum += v[q]; }
    red[t] = sum; __syncthreads();
    for (int s2 = 128; s2 > 0; s2 >>= 1) {
        if (t < s2) red[t] += red[t + s2];
        __syncthreads();
    }
    float inv = 1.f / red[0];
#pragma unroll
    for (int q = 0; q < 4; ++q) A[(size_t)n*N_NODES + q*256 + t] = v[q]*inv;
}

// gwT[e][o][kc] <- gwl[e][kc][o]  (tiny one-time transpose per layer weight)
template<int OUT>
__global__ __launch_bounds__(256) void wtrans_k(
    const float* __restrict__ gwl, float* __restrict__ gwT)
{
    int idx = blockIdx.x*256 + threadIdx.x;   // e*OUT*256 total, exact grid
    int kc = idx & 255;
    int rest = idx >> 8;
    int o = rest % OUT;
    int e = rest / OUT;
    gwT[idx] = gwl[((size_t)e*256 + kc)*OUT + o];
}

// W[n][o][kc] = sum_e emb[n][e]*gwT[e][o][kc], i16-quantized with per-(n,o) row scale.
template<int OUT>
__global__ __launch_bounds__(256) void wnodeq2_k(
    const float* __restrict__ emb, const float* __restrict__ gwT,
    short* __restrict__ WQ, float* __restrict__ wsc)
{
    int t = threadIdx.x;
    int n0 = blockIdx.x * 4;
    int lane = t & 63, w = t >> 6;
    __shared__ float se[4][EMB];
    if (t < 4*EMB) se[t >> 4][t & 15] = emb[(n0 + (t >> 4))*EMB + (t & 15)];
    __syncthreads();
    for (int o = w; o < OUT; o += 4) {
        const float* gp = gwT + (size_t)o*256 + lane*4;
        float4 s[4];
#pragma unroll
        for (int ng = 0; ng < 4; ++ng) s[ng] = make_float4(0.f, 0.f, 0.f, 0.f);
#pragma unroll
        for (int e = 0; e < EMB; ++e) {
            float4 g = *(const float4*)(gp + (size_t)e*(OUT*256));
#pragma unroll
            for (int ng = 0; ng < 4; ++ng) {
                float c = se[ng][e];
                s[ng].x += c*g.x; s[ng].y += c*g.y; s[ng].z += c*g.z; s[ng].w += c*g.w;
            }
        }
#pragma unroll
        for (int ng = 0; ng < 4; ++ng) {
            float amax = fmaxf(fmaxf(fabsf(s[ng].x), fabsf(s[ng].y)),
                               fmaxf(fabsf(s[ng].z), fabsf(s[ng].w)));
#pragma unroll
            for (int d = 32; d > 0; d >>= 1) amax = fmaxf(amax, __shfl_xor(amax, d));
            float inv = (amax > 0.f) ? 32767.f/amax : 0.f;
            short4_t q;
            q.x = (short)__float2int_rn(s[ng].x*inv);
            q.y = (short)__float2int_rn(s[ng].y*inv);
            q.z = (short)__float2int_rn(s[ng].z*inv);
            q.w = (short)__float2int_rn(s[ng].w*inv);
            *(short4_t*)(WQ + ((size_t)(n0+ng)*OUT + o)*256 + lane*4) = q;
            if (lane == 0) wsc[(n0+ng)*OUT + o] = (amax > 0.f) ? amax/32767.f : 0.f;
        }
    }
}

__global__ __launch_bounds__(256) void bias_k(const float* __restrict__ emb,
                        const float* __restrict__ gbl, float* __restrict__ bn, int OUT)
{
    int idx = blockIdx.x*256 + threadIdx.x;
    if (idx >= N_NODES*OUT) return;
    int n = idx / OUT, o = idx % OUT;
    float s = 0.f;
#pragma unroll
    for (int e = 0; e < EMB; ++e) s += emb[n*EMB + e]*gbl[e*OUT + o];
    bn[idx] = s;
}

// Fused pre-gate GEMM pair, split-K=2.
// z = blockIdx.z + zoff in 0..3: job = z>>1 (0: A@h -> pAh, 1: A@x(i16) -> pAx), ks = z&1.
// Each block: 64x64 tile over K in [ks*512, ks*512+512); partial ks written to +ks*1M elems.
__global__ __launch_bounds__(256) void gemmpair_k(
    const float* __restrict__ Amat, const float* __restrict__ hst,
    const short* __restrict__ xqp, const float* __restrict__ xscp,
    float* __restrict__ pAh, float* __restrict__ pAx, int zoff)
{
    __shared__ float As[16][68];
    __shared__ float Bs[16][68];
    int z = blockIdx.z + zoff;
    int job = z >> 1, ks = z & 1;
    int kbase = ks << 9;
    float* out = (job ? pAx : pAh) + ((size_t)ks << 20);
    int tid = threadIdx.x;
    int tx = tid & 15, ty = tid >> 4;
    int rowBase = blockIdx.y*64, colBase = blockIdx.x*64;
    float acc[4][4];
#pragma unroll
    for (int i = 0; i < 4; ++i)
#pragma unroll
        for (int j = 0; j < 4; ++j) acc[i][j] = 0.f;
    int lr = tid >> 2, lkq = tid & 3;
    int lk = tid >> 4, lj = (tid & 15) * 4;
    for (int k0 = 0; k0 < 512; k0 += 16) {
        float4 a4 = *(const float4*)(Amat + (size_t)(rowBase + lr)*1024 + kbase + k0 + lkq*4);
        As[lkq*4+0][lr] = a4.x; As[lkq*4+1][lr] = a4.y;
        As[lkq*4+2][lr] = a4.z; As[lkq*4+3][lr] = a4.w;
        int m = kbase + k0 + lk, j = colBase + lj;
        float4 b4;
        if (job == 0) {
            b4 = *(const float4*)(hst + (size_t)m*1024 + j);
        } else {
            short4_t q4 = *(const short4_t*)(xqp + (size_t)m*1024 + j);
            float s = xscp[m];
            b4 = make_float4((float)q4.x*s, (float)q4.y*s, (float)q4.z*s, (float)q4.w*s);
        }
        *(float4*)(&Bs[lk][lj]) = b4;
        __syncthreads();
#pragma unroll
        for (int kk = 0; kk < 16; ++kk) {
            float4 av = *(const float4*)(&As[kk][ty*4]);
            float4 bv = *(const float4*)(&Bs[kk][tx*4]);
            acc[0][0] += av.x*bv.x; acc[0][1] += av.x*bv.y; acc[0][2] += av.x*bv.z; acc[0][3] += av.x*bv.w;
            acc[1][0] += av.y*bv.x; acc[1][1] += av.y*bv.y; acc[1][2] += av.y*bv.z; acc[1][3] += av.y*bv.w;
            acc[2][0] += av.z*bv.x; acc[2][1] += av.z*bv.y; acc[2][2] += av.z*bv.z; acc[2][3] += av.z*bv.w;
            acc[3][0] += av.w*bv.x; acc[3][1] += av.w*bv.y; acc[3][2] += av.w*bv.z; acc[3][3] += av.w*bv.w;
        }
        __syncthreads();
    }
#pragma unroll
    for (int i = 0; i < 4; ++i)
        *(float4*)(out + (size_t)(rowBase + ty*4 + i)*1024 + colBase + tx*4) =
            make_float4(acc[i][0], acc[i][1], acc[i][2], acc[i][3]);
}

// A@(z*h), split-K=2 over blockIdx.z; z from zrb [m][b][128] (first half), h from hst.
__global__ __launch_bounds__(256) void gemmzh_k(
    const float* __restrict__ Amat, const float* __restrict__ zrb,
    const float* __restrict__ hst, float* __restrict__ pAzh)
{
    __shared__ float As[16][68];
    __shared__ float Bs[16][68];
    int ks = blockIdx.z;
    int kbase = ks << 9;
    float* out = pAzh + ((size_t)ks << 20);
    int tid = threadIdx.x;
    int tx = tid & 15, ty = tid >> 4;
    int rowBase = blockIdx.y*64, colBase = blockIdx.x*64;
    float acc[4][4];
#pragma unroll
    for (int i = 0; i < 4; ++i)
#pragma unroll
        for (int j = 0; j < 4; ++j) acc[i][j] = 0.f;
    int lr = tid >> 2, lkq = tid & 3;
    int lk = tid >> 4, lj = (tid & 15) * 4;
    for (int k0 = 0; k0 < 512; k0 += 16) {
        float4 a4 = *(const float4*)(Amat + (size_t)(rowBase + lr)*1024 + kbase + k0 + lkq*4);
        As[lkq*4+0][lr] = a4.x; As[lkq*4+1][lr] = a4.y;
        As[lkq*4+2][lr] = a4.z; As[lkq*4+3][lr] = a4.w;
        int m = kbase + k0 + lk, j = colBase + lj;
        float4 z4 = *(const float4*)(zrb + ((size_t)m*16 + (j >> 6))*128 + (j & 63));
        float4 h4 = *(const float4*)(hst + (size_t)m*1024 + j);
        *(float4*)(&Bs[lk][lj]) = make_float4(z4.x*h4.x, z4.y*h4.y, z4.z*h4.z, z4.w*h4.w);
        __syncthreads();
#pragma unroll
        for (int kk = 0; kk < 16; ++kk) {
            float4 av = *(const float4*)(&As[kk][ty*4]);
            float4 bv = *(const float4*)(&Bs[kk][tx*4]);
            acc[0][0] += av.x*bv.x; acc[0][1] += av.x*bv.y; acc[0][2] += av.x*bv.z; acc[0][3] += av.x*bv.w;
            acc[1][0] += av.y*bv.x; acc[1][1] += av.y*bv.y; acc[1][2] += av.y*bv.z; acc[1][3] += av.y*bv.w;
            acc[2][0] += av.z*bv.x; acc[2][1] += av.z*bv.y; acc[2][2] += av.z*bv.z; acc[2][3] += av.z*bv.w;
            acc[3][0] += av.w*bv.x; acc[3][1] += av.w*bv.y; acc[3][2] += av.w*bv.z; acc[3][3] += av.w*bv.w;
        }
        __syncthreads();
    }
#pragma unroll
    for (int i = 0; i < 4; ++i)
        *(float4*)(out + (size_t)(rowBase + ty*4 + i)*1024 + colBase + tx*4) =
            make_float4(acc[i][0], acc[i][1], acc[i][2], acc[i][3]);
}

// zr[n][b][o] = sigmoid( [x,h,Ax,Ah](n,b,:) · Wq[n](o,:)·ws[n][o] + bg[n][o] )
// Ax/Ah come as split-K partial pairs (base, base+1M). FIRST: h = Ah = 0.
template<int FIRST>
__global__ __launch_bounds__(256) void gate_k(
    const short* __restrict__ xq, const float* __restrict__ xsc,
    const float* __restrict__ hst, const float* __restrict__ pAx,
    const float* __restrict__ pAh, const short* __restrict__ WQ,
    const float* __restrict__ wsc, const float* __restrict__ bg,
    float* __restrict__ zr)
{
    __shared__ float inp[16*256];
    int n = blockIdx.x, t = threadIdx.x;
    size_t nb = (size_t)n*1024;
    float sx = xsc[n];
    for (int i = t; i < 1024; i += 256) {
        int b = i >> 6, c = i & 63;
        inp[b*256 + c]       = (float)xq[nb + i] * sx;
        inp[b*256 + 64 + c]  = FIRST ? 0.f : hst[nb + i];
        inp[b*256 + 128 + c] = pAx[nb + i] + pAx[nb + i + 1048576];
        inp[b*256 + 192 + c] = FIRST ? 0.f : (pAh[nb + i] + pAh[nb + i + 1048576]);
    }
    __syncthreads();
    int o = t & 127, g = t >> 7;
    const short* w = WQ + ((size_t)n*128 + o)*256;
    float ws = wsc[n*128 + o];
    float bias = bg[n*128 + o];
    float acc[8];
#pragma unroll
    for (int u = 0; u < 8; ++u) acc[u] = 0.f;
    for (int k0 = 0; k0 < 256; k0 += 4) {
        short4_t w4 = *(const short4_t*)(w + k0);
        float w0 = (float)w4.x, w1 = (float)w4.y, w2 = (float)w4.z, w3 = (float)w4.w;
#pragma unroll
        for (int u = 0; u < 8; ++u) {
            float4 iv = *(const float4*)(&inp[(g*8 + u)*256 + k0]);
            acc[u] += w0*iv.x + w1*iv.y + w2*iv.z + w3*iv.w;
        }
    }
#pragma unroll
    for (int u = 0; u < 8; ++u) {
        int b = g*8 + u;
        float pre = acc[u]*ws + bias;
        zr[((size_t)n*16 + b)*128 + o] = 1.f/(1.f + expf(-pre));
    }
}

// h_new = r*h + (1-r)*tanh([x, z*h, Ax, A(z*h)]·Wu[n]·ws[n][o] + bu)
// Azh comes as split-K partial pair. FIRST: h = Azh = 0.
template<int FIRST>
__global__ __launch_bounds__(256) void upd_k(
    short* __restrict__ xq, float* __restrict__ xsc,
    float* __restrict__ hst, const float* __restrict__ pAx,
    const float* __restrict__ pAzh, const float* __restrict__ zr,
    const short* __restrict__ WQ, const float* __restrict__ wsc,
    const float* __restrict__ bu)
{
    __shared__ float inp[16*256];
    int n = blockIdx.x, t = threadIdx.x;
    size_t nb = (size_t)n*1024;
    float sx = xsc[n];
    for (int i = t; i < 1024; i += 256) {
        int b = i >> 6, c = i & 63;
        float hv = FIRST ? 0.f : hst[nb + i];
        float zv = zr[((size_t)n*16 + b)*128 + c];
        inp[b*256 + c]       = (float)xq[nb + i] * sx;
        inp[b*256 + 64 + c]  = zv * hv;
        inp[b*256 + 128 + c] = pAx[nb + i] + pAx[nb + i + 1048576];
        inp[b*256 + 192 + c] = FIRST ? 0.f : (pAzh[nb + i] + pAzh[nb + i + 1048576]);
    }
    __syncthreads();
    int o = t & 63, g = t >> 6;
    const short* w = WQ + ((size_t)n*64 + o)*256;
    float ws = wsc[n*64 + o];
    float bias = bu[n*64 + o];
    float acc[4];
#pragma unroll
    for (int u = 0; u < 4; ++u) acc[u] = 0.f;
    for (int k0 = 0; k0 < 256; k0 += 4) {
        short4_t w4 = *(const short4_t*)(w + k0);
        float w0 = (float)w4.x, w1 = (float)w4.y, w2 = (float)w4.z, w3 = (float)w4.w;
#pragma unroll
        for (int u = 0; u < 4; ++u) {
            float4 iv = *(const float4*)(&inp[(g*4 + u)*256 + k0]);
            acc[u] += w0*iv.x + w1*iv.y + w2*iv.z + w3*iv.w;
        }
    }
#pragma unroll
    for (int u = 0; u < 4; ++u) {
        int b = g*4 + u;
        float r = zr[((size_t)n*16 + b)*128 + 64 + o];
        float hold = FIRST ? 0.f : hst[nb + b*64 + o];
        float hc = tanhf(acc[u]*ws + bias);
        float hn = r*hold + (1.f - r)*hc;
        hst[nb + b*64 + o] = hn;
        xq[nb + b*64 + o] = (short)__float2int_rn(hn*32767.f);
    }
    if (t == 0) xsc[n] = 1.f/32767.f;
}

// out[b][o][n] = h[n][b][:]·ecw[o][:] + ecb[o]
__global__ __launch_bounds__(256) void endconv_k(
    const float* __restrict__ hst, const float* __restrict__ ecw,
    const float* __restrict__ ecb, float* __restrict__ out)
{
    int idx = blockIdx.x*256 + threadIdx.x;   // 196608
    int n = idx & 1023;
    int o = (idx >> 10) % HOR;
    int b = idx / (HOR*1024);
    float s = ecb[o];
#pragma unroll
    for (int hh = 0; hh < 64; ++hh)
        s += hst[((size_t)n*16 + b)*64 + hh] * ecw[o*64 + hh];
    out[idx] = s;
}

extern "C" void kernel_launch(void* const* d_in, const int* in_sizes, int n_in,
                              void* d_out, int out_size, void* d_ws, size_t ws_size,
                              hipStream_t stream)
{
    const float* source = (const float*)d_in[0];
    const float* emb    = (const float*)d_in[2];
    const float* vw     = (const float*)d_in[3];
    const float* gate_w = (const float*)d_in[4];
    const float* gate_b = (const float*)d_in[5];
    const float* upd_w  = (const float*)d_in[6];
    const float* upd_b  = (const float*)d_in[7];
    const float* ecw    = (const float*)d_in[8];
    const float* ecb    = (const float*)d_in[9];
    float* out = (float*)d_out;

    // ---- workspace carve: ~186 MB ----
    char* p = (char*)d_ws;
    float* A    = (float*)p;  p += (size_t)1048576*4;        //   4.0 MB
    short* WgQ  = (short*)p;  p += (size_t)33554432*2;       //  64.0 MB  [n][128][256] i16
    short* WuQ  = (short*)p;  p += (size_t)16777216*2;       //  32.0 MB  [n][64][256] i16
    float* swg  = (float*)p;  p += (size_t)131072*4;         //   0.5 MB  per (n,o)
    float* swu  = (float*)p;  p += (size_t)65536*4;          //   0.25 MB per (n,o)
    float* bgn  = (float*)p;  p += (size_t)131072*4;         //   0.5 MB
    float* bun  = (float*)p;  p += (size_t)65536*4;          //   0.25 MB
    short* xq   = (short*)p;  p += (size_t)25165824*2;       //  48.0 MB  [p][n][b][h] i16
    float* xsc  = (float*)p;  p += (size_t)24576*4;          //   0.1 MB  per (p,n)
    float* hbuf = (float*)p;  p += (size_t)1048576*4;        //   4.0 MB
    float* zrb  = (float*)p;  p += (size_t)2097152*4;        //   8.0 MB
    float* pbuf = (float*)p;  p += (size_t)6291456*4;        //  24.0 MB  split-K partials
    float* pAh  = pbuf;                 // 2 x 1M
    float* pAx  = pbuf + 2097152;       // 2 x 1M
    float* pAzh = pbuf + 4194304;       // 2 x 1M
    float* gwT  = pbuf;                 // 2 MB scratch, aliases partials (layer setup only)

    embedq_k<<<24576, 256, 0, stream>>>(source, vw, xq, xsc);
    adj_k<<<1024, 256, 0, stream>>>(emb, A);

    for (int l = 0; l < 2; ++l) {
        wtrans_k<128><<<2048, 256, 0, stream>>>(gate_w + (size_t)l*524288, gwT);
        wnodeq2_k<128><<<256, 256, 0, stream>>>(emb, gwT, WgQ, swg);
        wtrans_k<64><<<1024, 256, 0, stream>>>(upd_w + (size_t)l*262144, gwT);
        wnodeq2_k<64><<<256, 256, 0, stream>>>(emb, gwT, WuQ, swu);
        bias_k<<<512, 256, 0, stream>>>(emb, gate_b + l*2048, bgn, 128);
        bias_k<<<256, 256, 0, stream>>>(emb, upd_b + l*1024, bun, 64);
        for (int ps = 0; ps < PWIN; ++ps) {
            short* xq_p  = xq  + (size_t)ps*NBH;
            float* xsc_p = xsc + (size_t)ps*1024;
            if (ps == 0) {
                // h == 0: only A@x needed; gate/upd FIRST variants treat h, Ah, Azh as 0
                gemmpair_k<<<dim3(16,16,2), 256, 0, stream>>>(A, hbuf, xq_p, xsc_p, pAh, pAx, 2);
                gate_k<1><<<1024, 256, 0, stream>>>(xq_p, xsc_p, hbuf, pAx, pAh, WgQ, swg, bgn, zrb);
                upd_k<1><<<1024, 256, 0, stream>>>(xq_p, xsc_p, hbuf, pAx, pAzh, zrb, WuQ, swu, bun);
            } else {
                gemmpair_k<<<dim3(16,16,4), 256, 0, stream>>>(A, hbuf, xq_p, xsc_p, pAh, pAx, 0);
                gate_k<0><<<1024, 256, 0, stream>>>(xq_p, xsc_p, hbuf, pAx, pAh, WgQ, swg, bgn, zrb);
                gemmzh_k<<<dim3(16,16,2), 256, 0, stream>>>(A, zrb, hbuf, pAzh);
                upd_k<0><<<1024, 256, 0, stream>>>(xq_p, xsc_p, hbuf, pAx, pAzh, zrb, WuQ, swu, bun);
            }
        }
    }
    endconv_k<<<768, 256, 0, stream>>>(hbuf, ecw, ecb, out);
}

// Round 3
// 5436.490 us; speedup vs baseline: 2.7636x; 1.4564x over previous
//
#include <hip/hip_runtime.h>
#include <math.h>

#define N_NODES 1024
#define HID 64
#define BATCH 16
#define TSTEPS 288
#define PWIN 24
#define PL 12
#define EMB 16
#define HOR 12
#define NBH (N_NODES*BATCH*HID)   // 1048576 elems per time-slice

typedef __attribute__((ext_vector_type(4))) short short4_t;
typedef _Float16 f16x8 __attribute__((ext_vector_type(8)));
typedef _Float16 f16x4 __attribute__((ext_vector_type(4)));
typedef float f32x4 __attribute__((ext_vector_type(4)));

// block per (p,n): x[p][n][b][h] = sum_t src[b, p*12+t, n]*vw[t,h] + pe[p,h]
// quantized to i16 with per-(p,n) amax scale
__global__ __launch_bounds__(256) void embedq_k(
    const float* __restrict__ src, const float* __restrict__ vw,
    short* __restrict__ xq, float* __restrict__ xsc)
{
    int blk = blockIdx.x;            // p*1024 + n
    int p = blk >> 10, n = blk & 1023;
    int t = threadIdx.x;
    __shared__ float sv[192];
    __shared__ float wv[PL*HID];
    __shared__ float red[256];
    if (t < 192) {
        int b = t / 12, tt = t % 12;
        sv[t] = src[((size_t)b*TSTEPS + p*PL + tt)*N_NODES + n];
    }
    for (int i = t; i < PL*HID; i += 256) wv[i] = vw[i];
    __syncthreads();
    float vals[4]; float amax = 0.f;
#pragma unroll
    for (int q = 0; q < 4; ++q) {
        int i = q*256 + t;           // b*64 + h
        int b = i >> 6, h = i & 63;
        float acc = 0.f;
#pragma unroll
        for (int tt = 0; tt < PL; ++tt) acc += sv[b*12 + tt] * wv[tt*HID + h];
        float d = expf(-(float)(h & ~1) * (float)(9.210340371976184/64.0));
        float arg = (float)p * d;
        acc += (h & 1) ? cosf(arg) : sinf(arg);
        vals[q] = acc; amax = fmaxf(amax, fabsf(acc));
    }
    red[t] = amax; __syncthreads();
    for (int s2 = 128; s2 > 0; s2 >>= 1) {
        if (t < s2) red[t] = fmaxf(red[t], red[t + s2]);
        __syncthreads();
    }
    amax = red[0];
    float inv = (amax > 0.f) ? 32767.f/amax : 0.f;
    short* xp = xq + (size_t)blk*1024;
#pragma unroll
    for (int q = 0; q < 4; ++q)
        xp[q*256 + t] = (short)__float2int_rn(vals[q]*inv);
    if (t == 0) xsc[blk] = (amax > 0.f) ? amax/32767.f : 0.f;
}

// A[n][m] = softmax_m(relu(emb[n]·emb[m])), written as f16 hi/lo pair (compensated)
__global__ __launch_bounds__(256) void adj_k(const float* __restrict__ emb,
    _Float16* __restrict__ Ahi, _Float16* __restrict__ Alo)
{
    __shared__ float en[EMB];
    __shared__ float red[256];
    int n = blockIdx.x, t = threadIdx.x;
    if (t < EMB) en[t] = emb[n*EMB + t];
    __syncthreads();
    float v[4]; float mx = 0.f;
#pragma unroll
    for (int q = 0; q < 4; ++q) {
        int m = q*256 + t;
        float dot = 0.f;
#pragma unroll
        for (int e = 0; e < EMB; ++e) dot += en[e]*emb[m*EMB + e];
        v[q] = fmaxf(dot, 0.f);
        mx = fmaxf(mx, v[q]);
    }
    red[t] = mx; __syncthreads();
    for (int s2 = 128; s2 > 0; s2 >>= 1) {
        if (t < s2) red[t] = fmaxf(red[t], red[t + s2]);
        __syncthreads();
    }
    mx = red[0]; __syncthreads();
    float sum = 0.f;
#pragma unroll
    for (int q = 0; q < 4; ++q) { v[q] = expf(v[q] - mx); sum += v[q]; }
    red[t] = sum; __syncthreads();
    for (int s2 = 128; s2 > 0; s2 >>= 1) {
        if (t < s2) red[t] += red[t + s2];
        __syncthreads();
    }
    float inv = 1.f / red[0];
#pragma unroll
    for (int q = 0; q < 4; ++q) {
        float av = v[q]*inv;
        _Float16 hi = (_Float16)av;
        size_t idx = (size_t)n*N_NODES + q*256 + t;
        Ahi[idx] = hi;
        Alo[idx] = (_Float16)(av - (float)hi);
    }
}

// gwT[e][o][kc] <- gwl[e][kc][o]
template<int OUT>
__global__ __launch_bounds__(256) void wtrans_k(
    const float* __restrict__ gwl, float* __restrict__ gwT)
{
    int idx = blockIdx.x*256 + threadIdx.x;
    int kc = idx & 255;
    int rest = idx >> 8;
    int o = rest % OUT;
    int e = rest / OUT;
    gwT[idx] = gwl[((size_t)e*256 + kc)*OUT + o];
}

// W[n][o][kc] = sum_e emb[n][e]*gwT[e][o][kc], i16 with per-(n,o) row scale.
// grid (256, 2): blockIdx.y splits the o-range for 2 blocks/CU.
template<int OUT>
__global__ __launch_bounds__(256) void wnodeq2_k(
    const float* __restrict__ emb, const float* __restrict__ gwT,
    short* __restrict__ WQ, float* __restrict__ wsc)
{
    int t = threadIdx.x;
    int n0 = blockIdx.x * 4;
    int oh = blockIdx.y;
    int lane = t & 63, w = t >> 6;
    __shared__ float se[4][EMB];
    if (t < 4*EMB) se[t >> 4][t & 15] = emb[(n0 + (t >> 4))*EMB + (t & 15)];
    __syncthreads();
    for (int o = oh*(OUT/2) + w; o < (oh+1)*(OUT/2); o += 4) {
        const float* gp = gwT + (size_t)o*256 + lane*4;
        float4 s[4];
#pragma unroll
        for (int ng = 0; ng < 4; ++ng) s[ng] = make_float4(0.f, 0.f, 0.f, 0.f);
#pragma unroll
        for (int e = 0; e < EMB; ++e) {
            float4 g = *(const float4*)(gp + (size_t)e*(OUT*256));
#pragma unroll
            for (int ng = 0; ng < 4; ++ng) {
                float c = se[ng][e];
                s[ng].x += c*g.x; s[ng].y += c*g.y; s[ng].z += c*g.z; s[ng].w += c*g.w;
            }
        }
#pragma unroll
        for (int ng = 0; ng < 4; ++ng) {
            float amax = fmaxf(fmaxf(fabsf(s[ng].x), fabsf(s[ng].y)),
                               fmaxf(fabsf(s[ng].z), fabsf(s[ng].w)));
#pragma unroll
            for (int d = 32; d > 0; d >>= 1) amax = fmaxf(amax, __shfl_xor(amax, d));
            float inv = (amax > 0.f) ? 32767.f/amax : 0.f;
            short4_t q;
            q.x = (short)__float2int_rn(s[ng].x*inv);
            q.y = (short)__float2int_rn(s[ng].y*inv);
            q.z = (short)__float2int_rn(s[ng].z*inv);
            q.w = (short)__float2int_rn(s[ng].w*inv);
            *(short4_t*)(WQ + ((size_t)(n0+ng)*OUT + o)*256 + lane*4) = q;
            if (lane == 0) wsc[(n0+ng)*OUT + o] = (amax > 0.f) ? amax/32767.f : 0.f;
        }
    }
}

__global__ __launch_bounds__(256) void bias_k(const float* __restrict__ emb,
                        const float* __restrict__ gbl, float* __restrict__ bn, int OUT)
{
    int idx = blockIdx.x*256 + threadIdx.x;
    if (idx >= N_NODES*OUT) return;
    int n = idx / OUT, o = idx % OUT;
    float s = 0.f;
#pragma unroll
    for (int e = 0; e < EMB; ++e) s += emb[n*EMB + e]*gbl[e*OUT + o];
    bn[idx] = s;
}

// Transpose to [j][m] f32: z=0: hT <- hbuf; z=1: xT <- xq*xsc. grid (16,16,nz)
__global__ __launch_bounds__(256) void transhx_k(
    const float* __restrict__ hsrc, const short* __restrict__ xsrc,
    const float* __restrict__ xscp, float* __restrict__ hT,
    float* __restrict__ xT, int zbase)
{
    int z = blockIdx.z + zbase;
    __shared__ float tile[64][65];
    int m0 = blockIdx.y*64, j0 = blockIdx.x*64;
    int t = threadIdx.x;
    if (z == 0) {
#pragma unroll
        for (int c = 0; c < 16; ++c) {
            int id = t + 256*c; int row = id >> 6, col = id & 63;
            tile[row][col] = hsrc[(size_t)(m0+row)*1024 + j0 + col];
        }
    } else {
#pragma unroll
        for (int c = 0; c < 16; ++c) {
            int id = t + 256*c; int row = id >> 6, col = id & 63;
            tile[row][col] = (float)xsrc[(size_t)(m0+row)*1024 + j0 + col] * xscp[m0+row];
        }
    }
    __syncthreads();
    float* dst = z ? xT : hT;
#pragma unroll
    for (int c = 0; c < 16; ++c) {
        int id = t + 256*c; int row = id >> 6, col = id & 63;
        dst[(size_t)(j0+row)*1024 + m0 + col] = tile[col][row];
    }
}

// zhT[j][m] = z(m,j)*h(m,j); z from zrb [m][b][128] cols 0..63
__global__ __launch_bounds__(256) void transzh_k(
    const float* __restrict__ zrb, const float* __restrict__ hbuf,
    float* __restrict__ zhT)
{
    __shared__ float tile[64][65];
    int m0 = blockIdx.y*64, j0 = blockIdx.x*64;
    int t = threadIdx.x;
#pragma unroll
    for (int c = 0; c < 16; ++c) {
        int id = t + 256*c; int row = id >> 6, col = id & 63;
        int m = m0 + row, j = j0 + col;
        int b = j >> 6, cc = j & 63;
        float zv = zrb[((size_t)m*16 + b)*128 + cc];
        tile[row][col] = zv * hbuf[(size_t)m*1024 + j];
    }
    __syncthreads();
#pragma unroll
    for (int c = 0; c < 16; ++c) {
        int id = t + 256*c; int row = id >> 6, col = id & 63;
        zhT[(size_t)(j0+row)*1024 + m0 + col] = tile[col][row];
    }
}

// C[r][j] = sum_m A[r][m]*B[m][j] via mfma_f32_16x16x32_f16, f32-emulated:
// A = Ahi+Alo (f16 pair, precomputed), B given TRANSPOSED f32 (BT[j][m]),
// split hi/lo during LDS staging. acc = Ahi*Bhi + Ahi*Blo + Alo*Bhi.
// Block: 64x64 tile, 4 waves (2x2), wave does 32x32 (2x2 frags).
// z = blockIdx.z + zbase selects (BT0,out0) or (BT1,out1).
__global__ __launch_bounds__(256) void gemm16_k(
    const _Float16* __restrict__ Ahi, const _Float16* __restrict__ Alo,
    const float* __restrict__ BT0, float* __restrict__ out0,
    const float* __restrict__ BT1, float* __restrict__ out1, int zbase)
{
    int z = blockIdx.z + zbase;
    const float* BT = z ? BT1 : BT0;
    float* out = z ? out1 : out0;
    __shared__ _Float16 Ash[64*72];
    __shared__ _Float16 Asl[64*72];
    __shared__ _Float16 Bsh[64*72];
    __shared__ _Float16 Bsl[64*72];
    int t = threadIdx.x;
    int l = t & 63, w = t >> 6;
    int wr = w >> 1, wc = w & 1;
    int r0 = blockIdx.y*64, c0 = blockIdx.x*64;
    f32x4 acc[2][2];
#pragma unroll
    for (int i = 0; i < 2; ++i)
#pragma unroll
        for (int j = 0; j < 2; ++j) acc[i][j] = (f32x4){0.f,0.f,0.f,0.f};
    int arow = wr*32 + (l & 15);
    int brow = wc*32 + (l & 15);
    int koff = (l >> 4)*8;
    for (int k0 = 0; k0 < 1024; k0 += 64) {
        __syncthreads();
#pragma unroll
        for (int c = 0; c < 2; ++c) {
            int id = t + 256*c;             // 0..511
            int row = id >> 3, k8 = id & 7;
            *(f16x8*)(&Ash[row*72 + k8*8]) =
                *(const f16x8*)(&Ahi[(size_t)(r0+row)*1024 + k0 + k8*8]);
            *(f16x8*)(&Asl[row*72 + k8*8]) =
                *(const f16x8*)(&Alo[(size_t)(r0+row)*1024 + k0 + k8*8]);
        }
#pragma unroll
        for (int c = 0; c < 4; ++c) {
            int id = t + 256*c;             // 0..1023
            int row = id >> 4, kq = id & 15;
            float4 v = *(const float4*)(&BT[(size_t)(c0+row)*1024 + k0 + kq*4]);
            float vv[4] = {v.x, v.y, v.z, v.w};
            f16x4 hi, lo;
#pragma unroll
            for (int i = 0; i < 4; ++i) {
                _Float16 h = (_Float16)vv[i];
                hi[i] = h;
                lo[i] = (_Float16)(vv[i] - (float)h);
            }
            *(f16x4*)(&Bsh[row*72 + kq*4]) = hi;
            *(f16x4*)(&Bsl[row*72 + kq*4]) = lo;
        }
        __syncthreads();
#pragma unroll
        for (int kk = 0; kk < 2; ++kk) {
            int ko = kk*32 + koff;
            f16x8 ah0 = *(const f16x8*)(&Ash[(size_t)arow*72 + ko]);
            f16x8 ah1 = *(const f16x8*)(&Ash[(size_t)(arow+16)*72 + ko]);
            f16x8 al0 = *(const f16x8*)(&Asl[(size_t)arow*72 + ko]);
            f16x8 al1 = *(const f16x8*)(&Asl[(size_t)(arow+16)*72 + ko]);
            f16x8 bh0 = *(const f16x8*)(&Bsh[(size_t)brow*72 + ko]);
            f16x8 bh1 = *(const f16x8*)(&Bsh[(size_t)(brow+16)*72 + ko]);
            f16x8 bl0 = *(const f16x8*)(&Bsl[(size_t)brow*72 + ko]);
            f16x8 bl1 = *(const f16x8*)(&Bsl[(size_t)(brow+16)*72 + ko]);
            acc[0][0] = __builtin_amdgcn_mfma_f32_16x16x32_f16(al0, bh0, acc[0][0], 0, 0, 0);
            acc[0][0] = __builtin_amdgcn_mfma_f32_16x16x32_f16(ah0, bl0, acc[0][0], 0, 0, 0);
            acc[0][0] = __builtin_amdgcn_mfma_f32_16x16x32_f16(ah0, bh0, acc[0][0], 0, 0, 0);
            acc[0][1] = __builtin_amdgcn_mfma_f32_16x16x32_f16(al0, bh1, acc[0][1], 0, 0, 0);
            acc[0][1] = __builtin_amdgcn_mfma_f32_16x16x32_f16(ah0, bl1, acc[0][1], 0, 0, 0);
            acc[0][1] = __builtin_amdgcn_mfma_f32_16x16x32_f16(ah0, bh1, acc[0][1], 0, 0, 0);
            acc[1][0] = __builtin_amdgcn_mfma_f32_16x16x32_f16(al1, bh0, acc[1][0], 0, 0, 0);
            acc[1][0] = __builtin_amdgcn_mfma_f32_16x16x32_f16(ah1, bl0, acc[1][0], 0, 0, 0);
            acc[1][0] = __builtin_amdgcn_mfma_f32_16x16x32_f16(ah1, bh0, acc[1][0], 0, 0, 0);
            acc[1][1] = __builtin_amdgcn_mfma_f32_16x16x32_f16(al1, bh1, acc[1][1], 0, 0, 0);
            acc[1][1] = __builtin_amdgcn_mfma_f32_16x16x32_f16(ah1, bl1, acc[1][1], 0, 0, 0);
            acc[1][1] = __builtin_amdgcn_mfma_f32_16x16x32_f16(ah1, bh1, acc[1][1], 0, 0, 0);
        }
    }
    // C/D layout: col = lane&15, row = 4*(lane>>4)+reg  [measured m89/m91]
#pragma unroll
    for (int fr = 0; fr < 2; ++fr)
#pragma unroll
        for (int fc = 0; fc < 2; ++fc) {
            int orow = r0 + wr*32 + fr*16 + ((l >> 4) << 2);
            int ocol = c0 + wc*32 + fc*16 + (l & 15);
#pragma unroll
            for (int i = 0; i < 4; ++i)
                out[(size_t)(orow+i)*1024 + ocol] = acc[fr][fc][i];
        }
}

// zr[n][b][o] = sigmoid( [x,h,Ax,Ah](n,b,:) · Wq[n](o,:)·ws[n][o] + bg[n][o] )
template<int FIRST>
__global__ __launch_bounds__(256) void gate_k(
    const short* __restrict__ xq, const float* __restrict__ xsc,
    const float* __restrict__ hst, const float* __restrict__ pAx,
    const float* __restrict__ pAh, const short* __restrict__ WQ,
    const float* __restrict__ wsc, const float* __restrict__ bg,
    float* __restrict__ zr)
{
    __shared__ float inp[16*256];
    int n = blockIdx.x, t = threadIdx.x;
    size_t nb = (size_t)n*1024;
    float sx = xsc[n];
    for (int i = t; i < 1024; i += 256) {
        int b = i >> 6, c = i & 63;
        inp[b*256 + c]       = (float)xq[nb + i] * sx;
        inp[b*256 + 64 + c]  = FIRST ? 0.f : hst[nb + i];
        inp[b*256 + 128 + c] = pAx[nb + i];
        inp[b*256 + 192 + c] = FIRST ? 0.f : pAh[nb + i];
    }
    __syncthreads();
    int o = t & 127, g = t >> 7;
    const short* wp = WQ + ((size_t)n*128 + o)*256;
    float ws = wsc[n*128 + o];
    float bias = bg[n*128 + o];
    float acc[8];
#pragma unroll
    for (int u = 0; u < 8; ++u) acc[u] = 0.f;
    for (int k0 = 0; k0 < 256; k0 += 4) {
        short4_t w4 = *(const short4_t*)(wp + k0);
        float w0 = (float)w4.x, w1 = (float)w4.y, w2 = (float)w4.z, w3 = (float)w4.w;
#pragma unroll
        for (int u = 0; u < 8; ++u) {
            float4 iv = *(const float4*)(&inp[(g*8 + u)*256 + k0]);
            acc[u] += w0*iv.x + w1*iv.y + w2*iv.z + w3*iv.w;
        }
    }
#pragma unroll
    for (int u = 0; u < 8; ++u) {
        int b = g*8 + u;
        float pre = acc[u]*ws + bias;
        zr[((size_t)n*16 + b)*128 + o] = 1.f/(1.f + expf(-pre));
    }
}

// h_new = r*h + (1-r)*tanh([x, z*h, Ax, A(z*h)]·Wu[n]·ws[n][o] + bu)
template<int FIRST>
__global__ __launch_bounds__(256) void upd_k(
    short* __restrict__ xq, float* __restrict__ xsc,
    float* __restrict__ hst, const float* __restrict__ pAx,
    const float* __restrict__ pAzh, const float* __restrict__ zr,
    const short* __restrict__ WQ, const float* __restrict__ wsc,
    const float* __restrict__ bu)
{
    __shared__ float inp[16*256];
    int n = blockIdx.x, t = threadIdx.x;
    size_t nb = (size_t)n*1024;
    float sx = xsc[n];
    for (int i = t; i < 1024; i += 256) {
        int b = i >> 6, c = i & 63;
        float hv = FIRST ? 0.f : hst[nb + i];
        float zv = zr[((size_t)n*16 + b)*128 + c];
        inp[b*256 + c]       = (float)xq[nb + i] * sx;
        inp[b*256 + 64 + c]  = zv * hv;
        inp[b*256 + 128 + c] = pAx[nb + i];
        inp[b*256 + 192 + c] = FIRST ? 0.f : pAzh[nb + i];
    }
    __syncthreads();
    int o = t & 63, g = t >> 6;
    const short* wp = WQ + ((size_t)n*64 + o)*256;
    float ws = wsc[n*64 + o];
    float bias = bu[n*64 + o];
    float acc[4];
#pragma unroll
    for (int u = 0; u < 4; ++u) acc[u] = 0.f;
    for (int k0 = 0; k0 < 256; k0 += 4) {
        short4_t w4 = *(const short4_t*)(wp + k0);
        float w0 = (float)w4.x, w1 = (float)w4.y, w2 = (float)w4.z, w3 = (float)w4.w;
#pragma unroll
        for (int u = 0; u < 4; ++u) {
            float4 iv = *(const float4*)(&inp[(g*4 + u)*256 + k0]);
            acc[u] += w0*iv.x + w1*iv.y + w2*iv.z + w3*iv.w;
        }
    }
#pragma unroll
    for (int u = 0; u < 4; ++u) {
        int b = g*4 + u;
        float r = zr[((size_t)n*16 + b)*128 + 64 + o];
        float hold = FIRST ? 0.f : hst[nb + b*64 + o];
        float hc = tanhf(acc[u]*ws + bias);
        float hn = r*hold + (1.f - r)*hc;
        hst[nb + b*64 + o] = hn;
        xq[nb + b*64 + o] = (short)__float2int_rn(hn*32767.f);
    }
    if (t == 0) xsc[n] = 1.f/32767.f;
}

// out[b][o][n] = h[n][b][:]·ecw[o][:] + ecb[o]
__global__ __launch_bounds__(256) void endconv_k(
    const float* __restrict__ hst, const float* __restrict__ ecw,
    const float* __restrict__ ecb, float* __restrict__ out)
{
    int idx = blockIdx.x*256 + threadIdx.x;
    int n = idx & 1023;
    int o = (idx >> 10) % HOR;
    int b = idx / (HOR*1024);
    float s = ecb[o];
#pragma unroll
    for (int hh = 0; hh < 64; ++hh)
        s += hst[((size_t)n*16 + b)*64 + hh] * ecw[o*64 + hh];
    out[idx] = s;
}

extern "C" void kernel_launch(void* const* d_in, const int* in_sizes, int n_in,
                              void* d_out, int out_size, void* d_ws, size_t ws_size,
                              hipStream_t stream)
{
    const float* source = (const float*)d_in[0];
    const float* emb    = (const float*)d_in[2];
    const float* vw     = (const float*)d_in[3];
    const float* gate_w = (const float*)d_in[4];
    const float* gate_b = (const float*)d_in[5];
    const float* upd_w  = (const float*)d_in[6];
    const float* upd_b  = (const float*)d_in[7];
    const float* ecw    = (const float*)d_in[8];
    const float* ecb    = (const float*)d_in[9];
    float* out = (float*)d_out;

    // ---- workspace carve: ~186 MB ----
    char* p = (char*)d_ws;
    _Float16* Ahi = (_Float16*)p; p += (size_t)1048576*2;    //   2.0 MB
    _Float16* Alo = (_Float16*)p; p += (size_t)1048576*2;    //   2.0 MB
    short* WgQ  = (short*)p;  p += (size_t)33554432*2;       //  64.0 MB
    short* WuQ  = (short*)p;  p += (size_t)16777216*2;       //  32.0 MB
    float* swg  = (float*)p;  p += (size_t)131072*4;         //   0.5 MB
    float* swu  = (float*)p;  p += (size_t)65536*4;          //   0.25 MB
    float* bgn  = (float*)p;  p += (size_t)131072*4;         //   0.5 MB
    float* bun  = (float*)p;  p += (size_t)65536*4;          //   0.25 MB
    short* xq   = (short*)p;  p += (size_t)25165824*2;       //  48.0 MB
    float* xsc  = (float*)p;  p += (size_t)24576*4;          //   0.1 MB
    float* hbuf = (float*)p;  p += (size_t)1048576*4;        //   4.0 MB
    float* zrb  = (float*)p;  p += (size_t)2097152*4;        //   8.0 MB
    float* hT   = (float*)p;  p += (size_t)1048576*4;        //   4.0 MB
    float* xT   = (float*)p;  p += (size_t)1048576*4;        //   4.0 MB
    float* zhT  = (float*)p;  p += (size_t)1048576*4;        //   4.0 MB
    float* Ah   = (float*)p;  p += (size_t)1048576*4;        //   4.0 MB
    float* Ax   = (float*)p;  p += (size_t)1048576*4;        //   4.0 MB
    float* Azh  = (float*)p;  p += (size_t)1048576*4;        //   4.0 MB
    float* gwT  = zhT;   // 2 MB scratch, aliases zhT (dead during layer setup)

    embedq_k<<<24576, 256, 0, stream>>>(source, vw, xq, xsc);
    adj_k<<<1024, 256, 0, stream>>>(emb, Ahi, Alo);

    for (int l = 0; l < 2; ++l) {
        wtrans_k<128><<<2048, 256, 0, stream>>>(gate_w + (size_t)l*524288, gwT);
        wnodeq2_k<128><<<dim3(256,2), 256, 0, stream>>>(emb, gwT, WgQ, swg);
        wtrans_k<64><<<1024, 256, 0, stream>>>(upd_w + (size_t)l*262144, gwT);
        wnodeq2_k<64><<<dim3(256,2), 256, 0, stream>>>(emb, gwT, WuQ, swu);
        bias_k<<<512, 256, 0, stream>>>(emb, gate_b + l*2048, bgn, 128);
        bias_k<<<256, 256, 0, stream>>>(emb, upd_b + l*1024, bun, 64);
        for (int ps = 0; ps < PWIN; ++ps) {
            short* xq_p  = xq  + (size_t)ps*NBH;
            float* xsc_p = xsc + (size_t)ps*1024;
            if (ps == 0) {
                // h == 0: only A@x path live
                transhx_k<<<dim3(16,16,1), 256, 0, stream>>>(hbuf, xq_p, xsc_p, hT, xT, 1);
                gemm16_k<<<dim3(16,16,1), 256, 0, stream>>>(Ahi, Alo, hT, Ah, xT, Ax, 1);
                gate_k<1><<<1024, 256, 0, stream>>>(xq_p, xsc_p, hbuf, Ax, Ah, WgQ, swg, bgn, zrb);
                upd_k<1><<<1024, 256, 0, stream>>>(xq_p, xsc_p, hbuf, Ax, Azh, zrb, WuQ, swu, bun);
            } else {
                transhx_k<<<dim3(16,16,2), 256, 0, stream>>>(hbuf, xq_p, xsc_p, hT, xT, 0);
                gemm16_k<<<dim3(16,16,2), 256, 0, stream>>>(Ahi, Alo, hT, Ah, xT, Ax, 0);
                gate_k<0><<<1024, 256, 0, stream>>>(xq_p, xsc_p, hbuf, Ax, Ah, WgQ, swg, bgn, zrb);
                transzh_k<<<dim3(16,16), 256, 0, stream>>>(zrb, hbuf, zhT);
                gemm16_k<<<dim3(16,16,1), 256, 0, stream>>>(Ahi, Alo, zhT, Azh, nullptr, nullptr, 0);
                upd_k<0><<<1024, 256, 0, stream>>>(xq_p, xsc_p, hbuf, Ax, Azh, zrb, WuQ, swu, bun);
            }
        }
    }
    endconv_k<<<768, 256, 0, stream>>>(hbuf, ecw, ecb, out);
}